// Round 6
// baseline (938.367 us; speedup 1.0000x reference)
//
#include <hip/hip_runtime.h>
#include <hip/hip_bf16.h>

#define NROWS   32768          // 32*16*64 rows of dim 64
#define NCODE   8192
#define NSPL    2              // code-dimension splits for the MFMA argmin

// d_out element offsets (FLOAT32 elements):
// quantize(2097152), ind(32768), loss(1), cluster(8192), eavg(524288), embed(524288)
#define OUT_Q        0
#define OUT_IND      2097152
#define OUT_LOSS     2129920
#define OUT_CLUSTER  2129921
#define OUT_EAVG     2138113
#define OUT_EMBED    2662401

// workspace byte offsets — total ~6.0 MB
#define WS_LOSS     0            // f32 [1] (zeroed)
#define WS_TOTAL    4            // f32 [1] (zeroed)
#define WS_SE       64           // f32 [8192]  ||e_j||^2
#define WS_COUNTS   32832        // f32 [8192]  (zeroed)
#define WS_IND      65600        // i32 [32768]
#define WS_ESUM     196672       // f32 [64*8192] (zeroed)
#define WS_PBEST    2293824      // f32 [2*32768] partial best dist
#define WS_PIDX     2555968      // i32 [2*32768] partial best idx
#define WS_BH       2818112      // bf16 bits [8192*64]  embed^T high split
#define WS_BM       3866688      // bf16 bits [8192*64]  mid split
#define WS_BL       4915264      // bf16 bits [8192*64]  low split
// end: 5,963,840 bytes

typedef short v8s __attribute__((ext_vector_type(8)));
typedef float v4f __attribute__((ext_vector_type(4)));
#define MFMA16 __builtin_amdgcn_mfma_f32_16x16x32_bf16

__device__ __forceinline__ int pos_off(int c, int R, int k) {
    // pos_emb[(R>>2)*16 + (k>>2)][c*16 + (R&3)*4 + (k&3)], row stride 256
    return (((R >> 2) * 16 + (k >> 2)) << 8) + (c << 4) + ((R & 3) << 2) + (k & 3);
}

__device__ __forceinline__ unsigned short f2bfbits(float v) {
    __hip_bfloat16 h = __float2bfloat16(v);           // RNE
    union { __hip_bfloat16 h; unsigned short u; } c; c.h = h; return c.u;
}
__device__ __forceinline__ float bfbits2f(unsigned short u) {
    union { unsigned short u; __hip_bfloat16 h; } c; c.u = u; return __bfloat162float(c.h);
}

// ---------------- K0: ind=0, ||e_j||^2 (bit-identical to R5), B' splits ---
__global__ __launch_bounds__(256) void k_prep_embed(
    const float* __restrict__ embed, float* __restrict__ se, int* __restrict__ ind,
    unsigned short* __restrict__ Bh, unsigned short* __restrict__ Bm,
    unsigned short* __restrict__ Bl)
{
    const int t = blockIdx.x * 256 + threadIdx.x;   // 128 blocks -> 0..32767
    ind[t] = 0;
    if (t < NCODE) {
        float s = 0.f;
#pragma unroll
        for (int k = 0; k < 64; ++k) {
            float v = embed[(size_t)k * NCODE + t];
            s = fmaf(v, v, s);                        // same order as R5 (passed)
            unsigned short uh = f2bfbits(v);  float r1 = v  - bfbits2f(uh);
            unsigned short um = f2bfbits(r1); float r2 = r1 - bfbits2f(um);
            unsigned short ul = f2bfbits(r2);
            Bh[t * 64 + k] = uh; Bm[t * 64 + k] = um; Bl[t * 64 + k] = ul;
        }
        se[t] = s;
    }
}

// ---------------- K1: MFMA GEMM-argmin (3-way bf16 split, 6 products) -----
// Grid 1024: blockIdx>>1 = 64-row block, blockIdx&1 = code split (4096).
// Block = 4 waves; wave w owns m-tile rows w*16..w*16+15, streams all n-tiles.
__global__ __launch_bounds__(256) void k_argmin_mfma(
    const float* __restrict__ x, const float* __restrict__ pos,
    const unsigned short* __restrict__ Bh, const unsigned short* __restrict__ Bm,
    const unsigned short* __restrict__ Bl, const float* __restrict__ se,
    float* __restrict__ part_best, int* __restrict__ part_idx)
{
    __shared__ unsigned short lA[3][64][72];   // 144B pitch: 16B-aligned frags, 2-way banks
    __shared__ float sx_s[64];
    const int tid  = threadIdx.x;
    const int row0  = (blockIdx.x >> 1) * 64;
    const int split = blockIdx.x & 1;
    const int w    = tid >> 6;
    const int lane = tid & 63;
    const int quad = lane >> 4, l15 = lane & 15;

    // stage q = x + pos, split into 3 bf16 parts; wave-reduce ||q_row||^2
#pragma unroll
    for (int p = 0; p < 16; ++p) {
        const int rr = p * 4 + w;                 // all 64 lanes: same row, k = lane
        const int k = lane;
        const int n = row0 + rr;
        const int c = (n >> 6) & 15, R = n & 63;
        float v = x[(size_t)n * 64 + k] + pos[pos_off(c, R, k)];
        unsigned short uh = f2bfbits(v);  float r1 = v  - bfbits2f(uh);
        unsigned short um = f2bfbits(r1); float r2 = r1 - bfbits2f(um);
        unsigned short ul = f2bfbits(r2);
        lA[0][rr][k] = uh; lA[1][rr][k] = um; lA[2][rr][k] = ul;
        float sq = v * v;                         // row-constant shift: argmin-invariant
#pragma unroll
        for (int m = 32; m >= 1; m >>= 1) sq += __shfl_xor(sq, m, 64);
        if (lane == 0) sx_s[rr] = sq;
    }
    __syncthreads();

    // A-frags held in registers: A[m=lane&15][k=quad*8+j] (+32 for kstep1)
    const int mrow = w * 16 + l15;
    const v8s ah0 = *(const v8s*)(&lA[0][mrow][quad * 8]);
    const v8s ah1 = *(const v8s*)(&lA[0][mrow][32 + quad * 8]);
    const v8s am0 = *(const v8s*)(&lA[1][mrow][quad * 8]);
    const v8s am1 = *(const v8s*)(&lA[1][mrow][32 + quad * 8]);
    const v8s al0 = *(const v8s*)(&lA[2][mrow][quad * 8]);
    const v8s al1 = *(const v8s*)(&lA[2][mrow][32 + quad * 8]);

    float sxr[4];                                 // C/D: row = quad*4 + reg
#pragma unroll
    for (int r = 0; r < 4; ++r) sxr[r] = sx_s[w * 16 + quad * 4 + r];

    float best[4]; int bidx[4];
#pragma unroll
    for (int r = 0; r < 4; ++r) { best[r] = 3.402823466e38f; bidx[r] = 0; }

    const int jbeg = split * (NCODE / NSPL);
    size_t jo = (size_t)(jbeg + l15) * 64 + quad * 8;   // B'[n][k] frag offset

    for (int nt = 0; nt < (NCODE / NSPL) / 16; ++nt) {
        const int n0 = jbeg + nt * 16;
        const v8s bh0 = *(const v8s*)(Bh + jo);
        const v8s bh1 = *(const v8s*)(Bh + jo + 32);
        const v8s bm0 = *(const v8s*)(Bm + jo);
        const v8s bm1 = *(const v8s*)(Bm + jo + 32);
        const v8s bl0 = *(const v8s*)(Bl + jo);
        const v8s bl1 = *(const v8s*)(Bl + jo + 32);
        const float sev = se[n0 + l15];

        v4f a1 = {0.f, 0.f, 0.f, 0.f}, a2 = {0.f, 0.f, 0.f, 0.f};
        a1 = MFMA16(al0, bh0, a1, 0, 0, 0);  a1 = MFMA16(al1, bh1, a1, 0, 0, 0);
        a1 = MFMA16(ah0, bl0, a1, 0, 0, 0);  a1 = MFMA16(ah1, bl1, a1, 0, 0, 0);
        a1 = MFMA16(am0, bm0, a1, 0, 0, 0);  a1 = MFMA16(am1, bm1, a1, 0, 0, 0);
        a2 = MFMA16(am0, bh0, a2, 0, 0, 0);  a2 = MFMA16(am1, bh1, a2, 0, 0, 0);
        a2 = MFMA16(ah0, bm0, a2, 0, 0, 0);  a2 = MFMA16(ah1, bm1, a2, 0, 0, 0);
        a2 = MFMA16(ah0, bh0, a2, 0, 0, 0);  a2 = MFMA16(ah1, bh1, a2, 0, 0, 0);

        const int j = n0 + l15;
#pragma unroll
        for (int r = 0; r < 4; ++r) {
            float d = fmaf(-2.f, a1[r], fmaf(-2.f, a2[r], sxr[r])) + sev;
            if (d < best[r]) { best[r] = d; bidx[r] = j; }
        }
        jo += 1024;                               // 16 codes * 64 k
    }

    // reduce across the 16 lanes holding the same output row (masks stay in-group)
#pragma unroll
    for (int r = 0; r < 4; ++r) {
        float bv = best[r]; int bi = bidx[r];
#pragma unroll
        for (int m = 8; m >= 1; m >>= 1) {
            float ov = __shfl_xor(bv, m, 64);
            int   oi = __shfl_xor(bi, m, 64);
            if (ov < bv || (ov == bv && oi < bi)) { bv = ov; bi = oi; }
        }
        if (l15 == 0) {
            const int row = row0 + w * 16 + quad * 4 + r;
            part_best[split * NROWS + row] = bv;
            part_idx [split * NROWS + row] = bi;
        }
    }
}

// ---------------- K1b: merge the split partials ---------------------------
__global__ __launch_bounds__(256) void k_reduce(
    const float* __restrict__ part_best, const int* __restrict__ part_idx,
    int* __restrict__ ind, float* __restrict__ out_ind)
{
    const int n = blockIdx.x * 256 + threadIdx.x;   // 128 blocks
    float bv = part_best[n];
    int   bi = part_idx[n];
#pragma unroll
    for (int s = 1; s < NSPL; ++s) {
        float v = part_best[s * NROWS + n];
        int   i = part_idx [s * NROWS + n];
        if (v < bv || (v == bv && i < bi)) { bv = v; bi = i; }  // lower idx wins ties
    }
    ind[n] = bi;
    out_ind[n] = (float)bi;
}

// ---------------- K2: quantize gather + loss + EMA scatter ----------------
__global__ __launch_bounds__(256) void k_quant(
    const float* __restrict__ x, const float* __restrict__ pos,
    const float* __restrict__ embed, const int* __restrict__ ind,
    float* __restrict__ embed_sum, float* __restrict__ counts,
    float* __restrict__ loss_ws, float* __restrict__ out_q)
{
    const int tid = threadIdx.x;
    const int rr = tid >> 6, k = tid & 63;       // 4 rows x 64 dims
    const int n = blockIdx.x * 4 + rr;
    int idx = ind[n];
    idx = idx < 0 ? 0 : (idx > NCODE - 1 ? NCODE - 1 : idx);  // defensive clamp
    const float qv = embed[(size_t)k * NCODE + idx];
    const float xv = x[(size_t)n * 64 + k];
    out_q[(size_t)n * 64 + k] = qv;

    const int c = (n >> 6) & 15, R = n & 63;
    const float fv = xv + pos[pos_off(c, R, k)];
    atomicAdd(&embed_sum[(size_t)k * NCODE + idx], fv);
    if (k == 0) atomicAdd(&counts[idx], 1.0f);

    float sq = (qv - xv) * (qv - xv);
#pragma unroll
    for (int m = 32; m >= 1; m >>= 1) sq += __shfl_xor(sq, m, 64);
    __shared__ float ls[4];
    if ((tid & 63) == 0) ls[tid >> 6] = sq;
    __syncthreads();
    if (tid == 0) atomicAdd(loss_ws, ls[0] + ls[1] + ls[2] + ls[3]);
}

// ---------------- K3a: new_cluster + total --------------------------------
__global__ __launch_bounds__(256) void k_final1(
    const float* __restrict__ cluster, const float* __restrict__ counts,
    float* __restrict__ total_ws, float* __restrict__ out_cluster)
{
    const int j = blockIdx.x * 256 + threadIdx.x;   // 32 blocks
    float nc = 0.8f * cluster[j] + 0.2f * counts[j];
    out_cluster[j] = nc;
    float s = nc;
#pragma unroll
    for (int m = 32; m >= 1; m >>= 1) s += __shfl_xor(s, m, 64);
    __shared__ float ls[4];
    if ((threadIdx.x & 63) == 0) ls[threadIdx.x >> 6] = s;
    __syncthreads();
    if (threadIdx.x == 0) atomicAdd(total_ws, ls[0] + ls[1] + ls[2] + ls[3]);
}

// ---------------- K3b: smoothed / new_embed_avg / new_embed / loss --------
__global__ __launch_bounds__(256) void k_final2(
    const float* __restrict__ cluster, const float* __restrict__ counts,
    const float* __restrict__ embed_avg, const float* __restrict__ embed_sum,
    const float* __restrict__ total_ws, const float* __restrict__ loss_ws,
    float* __restrict__ out_loss, float* __restrict__ out_eavg,
    float* __restrict__ out_embed)
{
    const int e = blockIdx.x * 256 + threadIdx.x;   // 2048 blocks -> 524288
    const int j = e & (NCODE - 1);
    const float total = *total_ws;
    float nc = 0.8f * cluster[j] + 0.2f * counts[j];
    float smoothed = (nc + 1e-5f) / (total + 0.08192f) * total;
    float ea = 0.8f * embed_avg[e] + 0.2f * embed_sum[e];
    out_eavg[e]  = ea;
    out_embed[e] = ea / smoothed;
    if (e == 0) *out_loss = *loss_ws * (1.0f / 2097152.0f);
}

extern "C" void kernel_launch(void* const* d_in, const int* in_sizes, int n_in,
                              void* d_out, int out_size, void* d_ws, size_t ws_size,
                              hipStream_t stream) {
    (void)in_sizes; (void)n_in; (void)out_size; (void)ws_size;
    const float* x        = (const float*)d_in[0];   // (32,16,64,64)
    const float* embed    = (const float*)d_in[1];   // (64,8192)
    const float* pos      = (const float*)d_in[2];   // (2048,256)
    const float* cluster  = (const float*)d_in[3];   // (8192,)
    const float* eavg     = (const float*)d_in[4];   // (64,8192)
    float* out = (float*)d_out;                      // fp32 outputs, concatenated

    char* ws = (char*)d_ws;
    float* w_loss   = (float*)(ws + WS_LOSS);
    float* w_total  = (float*)(ws + WS_TOTAL);
    float* w_se     = (float*)(ws + WS_SE);
    float* w_counts = (float*)(ws + WS_COUNTS);
    int*   w_ind    = (int*)  (ws + WS_IND);
    float* w_esum   = (float*)(ws + WS_ESUM);
    float* w_pbest  = (float*)(ws + WS_PBEST);
    int*   w_pidx   = (int*)  (ws + WS_PIDX);
    unsigned short* w_bh = (unsigned short*)(ws + WS_BH);
    unsigned short* w_bm = (unsigned short*)(ws + WS_BM);
    unsigned short* w_bl = (unsigned short*)(ws + WS_BL);

    // zero accumulators (ws is poisoned 0xAA before every launch)
    hipMemsetAsync(ws + WS_LOSS,   0, 8, stream);
    hipMemsetAsync(ws + WS_COUNTS, 0, 32768, stream);
    hipMemsetAsync(ws + WS_ESUM,   0, 2097152, stream);

    k_prep_embed<<<128, 256, 0, stream>>>(embed, w_se, w_ind, w_bh, w_bm, w_bl);
    k_argmin_mfma<<<(NROWS / 64) * NSPL, 256, 0, stream>>>(
        x, pos, w_bh, w_bm, w_bl, w_se, w_pbest, w_pidx);
    k_reduce<<<NROWS / 256, 256, 0, stream>>>(w_pbest, w_pidx, w_ind,
                                              out + OUT_IND);
    k_quant<<<NROWS / 4, 256, 0, stream>>>(x, pos, embed, w_ind, w_esum,
                                           w_counts, w_loss, out + OUT_Q);
    k_final1<<<NCODE / 256, 256, 0, stream>>>(cluster, w_counts, w_total,
                                              out + OUT_CLUSTER);
    k_final2<<<524288 / 256, 256, 0, stream>>>(cluster, w_counts, eavg, w_esum,
                                               w_total, w_loss, out + OUT_LOSS,
                                               out + OUT_EAVG, out + OUT_EMBED);
}

// Round 7
// 476.881 us; speedup vs baseline: 1.9677x; 1.9677x over previous
//
#include <hip/hip_runtime.h>
#include <hip/hip_bf16.h>

#define NROWS   32768          // 32*16*64 rows of dim 64
#define NCODE   8192

// d_out element offsets (FLOAT32 elements):
// quantize(2097152), ind(32768), loss(1), cluster(8192), eavg(524288), embed(524288)
#define OUT_Q        0
#define OUT_IND      2097152
#define OUT_LOSS     2129920
#define OUT_CLUSTER  2129921
#define OUT_EAVG     2138113
#define OUT_EMBED    2662401

// workspace byte offsets — total ~5.44 MB (R6 used 5.96 MB OK)
#define WS_LOSS     0            // f32 [1] (zeroed)
#define WS_TOTAL    4            // f32 [1] (zeroed)
#define WS_SE       64           // f32 [8192]  ||e_j||^2
#define WS_COUNTS   32832        // f32 [8192]  (zeroed)
#define WS_IND      65600        // i32 [32768]
#define WS_ESUM     196672       // f32 [8192][64]  ([code][k] layout, zeroed)
#define WS_BH       2293824      // bf16 bits [8192][64] embed^T high split
#define WS_BM       3342400      // bf16 bits [8192][64] mid split
#define WS_BL       4390976      // bf16 bits [8192][64] low split
// end: 5,439,552 bytes

typedef short v8s __attribute__((ext_vector_type(8)));
typedef float v4f __attribute__((ext_vector_type(4)));
#define MFMA16 __builtin_amdgcn_mfma_f32_16x16x32_bf16

__device__ __forceinline__ int pos_off(int c, int R, int k) {
    // pos_emb[(R>>2)*16 + (k>>2)][c*16 + (R&3)*4 + (k&3)], row stride 256
    return (((R >> 2) * 16 + (k >> 2)) << 8) + (c << 4) + ((R & 3) << 2) + (k & 3);
}

__device__ __forceinline__ unsigned short f2bfbits(float v) {
    __hip_bfloat16 h = __float2bfloat16(v);           // RNE
    union { __hip_bfloat16 h; unsigned short u; } c; c.h = h; return c.u;
}
__device__ __forceinline__ float bfbits2f(unsigned short u) {
    union { unsigned short u; __hip_bfloat16 h; } c; c.u = u; return __bfloat162float(c.h);
}

// ---------------- K0: ind=0, ||e_j||^2 (bit-identical chain), B' splits ---
__global__ __launch_bounds__(256) void k_prep_embed(
    const float* __restrict__ embed, float* __restrict__ se, int* __restrict__ ind,
    unsigned short* __restrict__ Bh, unsigned short* __restrict__ Bm,
    unsigned short* __restrict__ Bl)
{
    const int t = blockIdx.x * 256 + threadIdx.x;   // 128 blocks -> 0..32767
    ind[t] = 0;
    if (t < NCODE) {
        float s = 0.f;
#pragma unroll
        for (int k = 0; k < 64; ++k) {
            float v = embed[(size_t)k * NCODE + t];
            s = fmaf(v, v, s);                        // same order as R5/R6 (passed)
            unsigned short uh = f2bfbits(v);  float r1 = v  - bfbits2f(uh);
            unsigned short um = f2bfbits(r1); float r2 = r1 - bfbits2f(um);
            unsigned short ul = f2bfbits(r2);
            Bh[t * 64 + k] = uh; Bm[t * 64 + k] = um; Bl[t * 64 + k] = ul;
        }
        se[t] = s;
    }
}

// ---------------- K1: MFMA GEMM-argmin, LDS-shared B, double-buffered -----
// Grid 256 (1 block/CU): block owns 128 rows; wave owns 32 rows (2 m-tiles)
// and streams all 8192 codes in 32-code chunks staged cooperatively in LDS.
__global__ __launch_bounds__(256) void k_argmin_mfma(
    const float* __restrict__ x, const float* __restrict__ pos,
    const unsigned short* __restrict__ Bh, const unsigned short* __restrict__ Bm,
    const unsigned short* __restrict__ Bl, const float* __restrict__ se,
    int* __restrict__ ind, float* __restrict__ out_ind)
{
    // arena phase 1: A splits [3][128][72]; phase 2: B dbuf 2x[3][32][72]
    __shared__ __align__(16) short arena[27648];
    __shared__ float sx_s[128];
    const int tid = threadIdx.x;
    const int row0 = blockIdx.x * 128;
    const int w = tid >> 6, lane = tid & 63;
    const int quad = lane >> 4, l15 = lane & 15;

    // ---- stage A: q = x + pos, 3-way bf16 split (same math as R6), + norms
#pragma unroll 4
    for (int p = 0; p < 32; ++p) {
        const int rr = p * 4 + w;                 // all 64 lanes: one row, k = lane
        const int k = lane;
        const int n = row0 + rr;
        const int c = (n >> 6) & 15, R = n & 63;
        float v = x[(size_t)n * 64 + k] + pos[pos_off(c, R, k)];
        unsigned short uh = f2bfbits(v);  float r1 = v  - bfbits2f(uh);
        unsigned short um = f2bfbits(r1); float r2 = r1 - bfbits2f(um);
        unsigned short ul = f2bfbits(r2);
        arena[0 * 9216 + rr * 72 + k] = uh;
        arena[1 * 9216 + rr * 72 + k] = um;
        arena[2 * 9216 + rr * 72 + k] = ul;
        float sq = v * v;                         // row-constant: argmin-invariant
#pragma unroll
        for (int m = 32; m >= 1; m >>= 1) sq += __shfl_xor(sq, m, 64);
        if (lane == 0) sx_s[rr] = sq;
    }
    __syncthreads();

    // A-frags to registers: af[mtile][split h/m/l][khalf]; A[m=l15][k=quad*8+j]
    v8s af[2][3][2];
#pragma unroll
    for (int mt = 0; mt < 2; ++mt) {
        const int mrow = w * 32 + mt * 16 + l15;
#pragma unroll
        for (int s = 0; s < 3; ++s) {
            af[mt][s][0] = *(const v8s*)&arena[s * 9216 + mrow * 72 + quad * 8];
            af[mt][s][1] = *(const v8s*)&arena[s * 9216 + mrow * 72 + 32 + quad * 8];
        }
    }
    float sxr[2][4];
#pragma unroll
    for (int mt = 0; mt < 2; ++mt)
#pragma unroll
        for (int r = 0; r < 4; ++r)
            sxr[mt][r] = sx_s[w * 32 + mt * 16 + quad * 4 + r];
    __syncthreads();                              // arena-A reads done everywhere

    // ---- stream B in 32-code chunks, LDS double-buffer, reg prefetch ----
    const int ct = tid >> 3, ks = tid & 7;        // staging: code-in-chunk, 16B slot
    float best[2][4]; int bidx[2][4];
#pragma unroll
    for (int mt = 0; mt < 2; ++mt)
#pragma unroll
        for (int r = 0; r < 4; ++r) { best[mt][r] = 3.402823466e38f; bidx[mt][r] = 0; }

    {   // prologue: chunk 0 -> buf 0
        const size_t g = (size_t)ct * 64 + ks * 8;
        int4 p0 = *(const int4*)(Bh + g);
        int4 p1 = *(const int4*)(Bm + g);
        int4 p2 = *(const int4*)(Bl + g);
        const int d = ct * 72 + ks * 8;
        *(int4*)&arena[0 * 2304 + d] = p0;
        *(int4*)&arena[1 * 2304 + d] = p1;
        *(int4*)&arena[2 * 2304 + d] = p2;
    }
    float cse0 = se[l15], cse1 = se[16 + l15];
    __syncthreads();

    int buf = 0;
    for (int c = 0; c < 256; ++c) {
        int4 p0, p1, p2; float nse0 = 0.f, nse1 = 0.f;
        if (c < 255) {                            // prefetch next chunk to regs
            const int n0n = (c + 1) * 32;
            const size_t g = (size_t)(n0n + ct) * 64 + ks * 8;
            p0 = *(const int4*)(Bh + g);
            p1 = *(const int4*)(Bm + g);
            p2 = *(const int4*)(Bl + g);
            nse0 = se[n0n + l15]; nse1 = se[n0n + 16 + l15];
        }
        const short* bb = &arena[buf * 6912];
#pragma unroll
        for (int t16 = 0; t16 < 2; ++t16) {       // two 16-code n-tiles
            const int boff = (t16 * 16 + l15) * 72 + quad * 8;
            const v8s bh0 = *(const v8s*)&bb[0 * 2304 + boff];
            const v8s bh1 = *(const v8s*)&bb[0 * 2304 + boff + 32];
            const v8s bm0 = *(const v8s*)&bb[1 * 2304 + boff];
            const v8s bm1 = *(const v8s*)&bb[1 * 2304 + boff + 32];
            const v8s bl0 = *(const v8s*)&bb[2 * 2304 + boff];
            const v8s bl1 = *(const v8s*)&bb[2 * 2304 + boff + 32];
            const float sev = t16 ? cse1 : cse0;
            const int j = c * 32 + t16 * 16 + l15;
#pragma unroll
            for (int mt = 0; mt < 2; ++mt) {      // same 6-product chains as R6
                v4f a1 = {0.f, 0.f, 0.f, 0.f}, a2 = {0.f, 0.f, 0.f, 0.f};
                a1 = MFMA16(af[mt][2][0], bh0, a1, 0, 0, 0);
                a1 = MFMA16(af[mt][2][1], bh1, a1, 0, 0, 0);
                a1 = MFMA16(af[mt][0][0], bl0, a1, 0, 0, 0);
                a1 = MFMA16(af[mt][0][1], bl1, a1, 0, 0, 0);
                a1 = MFMA16(af[mt][1][0], bm0, a1, 0, 0, 0);
                a1 = MFMA16(af[mt][1][1], bm1, a1, 0, 0, 0);
                a2 = MFMA16(af[mt][1][0], bh0, a2, 0, 0, 0);
                a2 = MFMA16(af[mt][1][1], bh1, a2, 0, 0, 0);
                a2 = MFMA16(af[mt][0][0], bm0, a2, 0, 0, 0);
                a2 = MFMA16(af[mt][0][1], bm1, a2, 0, 0, 0);
                a2 = MFMA16(af[mt][0][0], bh0, a2, 0, 0, 0);
                a2 = MFMA16(af[mt][0][1], bh1, a2, 0, 0, 0);
#pragma unroll
                for (int r = 0; r < 4; ++r) {
                    float d = fmaf(-2.f, a1[r], fmaf(-2.f, a2[r], sxr[mt][r])) + sev;
                    if (d < best[mt][r]) { best[mt][r] = d; bidx[mt][r] = j; }
                }
            }
        }
        if (c < 255) {                            // store prefetch to other buf
            const int nb = buf ^ 1;
            const int d = ct * 72 + ks * 8;
            *(int4*)&arena[nb * 6912 + 0 * 2304 + d] = p0;
            *(int4*)&arena[nb * 6912 + 1 * 2304 + d] = p1;
            *(int4*)&arena[nb * 6912 + 2 * 2304 + d] = p2;
            cse0 = nse0; cse1 = nse1;
            __syncthreads();
            buf = nb;
        }
    }

    // reduce over the 16 lanes sharing each output row; lower idx wins ties
#pragma unroll
    for (int mt = 0; mt < 2; ++mt)
#pragma unroll
    for (int r = 0; r < 4; ++r) {
        float bv = best[mt][r]; int bi = bidx[mt][r];
#pragma unroll
        for (int m = 8; m >= 1; m >>= 1) {
            float ov = __shfl_xor(bv, m, 64);
            int   oi = __shfl_xor(bi, m, 64);
            if (ov < bv || (ov == bv && oi < bi)) { bv = ov; bi = oi; }
        }
        if (l15 == 0) {
            const int row = row0 + w * 32 + mt * 16 + quad * 4 + r;
            ind[row] = bi;
            out_ind[row] = (float)bi;
        }
    }
}

// ---------------- K2: quantize gather + loss + EMA scatter ----------------
// Gather from bf16 splits (coalesced 3x128B/row; exact fp32 sum to 2^-25).
__global__ __launch_bounds__(256) void k_quant(
    const float* __restrict__ x, const float* __restrict__ pos,
    const unsigned short* __restrict__ Bh, const unsigned short* __restrict__ Bm,
    const unsigned short* __restrict__ Bl, const int* __restrict__ ind,
    float* __restrict__ embed_sum, float* __restrict__ counts,
    float* __restrict__ loss_ws, float* __restrict__ out_q)
{
    const int tid = threadIdx.x;
    const int rr = tid >> 6, k = tid & 63;       // 4 rows x 64 dims
    const int n = blockIdx.x * 4 + rr;
    int idx = ind[n];
    idx = idx < 0 ? 0 : (idx > NCODE - 1 ? NCODE - 1 : idx);  // defensive clamp
    const size_t eo = (size_t)idx * 64 + k;
    const float qv = bfbits2f(Bh[eo]) + bfbits2f(Bm[eo]) + bfbits2f(Bl[eo]);
    const float xv = x[(size_t)n * 64 + k];
    out_q[(size_t)n * 64 + k] = qv;

    const int c = (n >> 6) & 15, R = n & 63;
    const float fv = xv + pos[pos_off(c, R, k)];
    atomicAdd(&embed_sum[eo], fv);               // [code][k] layout: 16 lines/row
    if (k == 0) atomicAdd(&counts[idx], 1.0f);

    float sq = (qv - xv) * (qv - xv);
#pragma unroll
    for (int m = 32; m >= 1; m >>= 1) sq += __shfl_xor(sq, m, 64);
    __shared__ float ls[4];
    if ((tid & 63) == 0) ls[tid >> 6] = sq;
    __syncthreads();
    if (tid == 0) atomicAdd(loss_ws, ls[0] + ls[1] + ls[2] + ls[3]);
}

// ---------------- K3a: new_cluster + total --------------------------------
__global__ __launch_bounds__(256) void k_final1(
    const float* __restrict__ cluster, const float* __restrict__ counts,
    float* __restrict__ total_ws, float* __restrict__ out_cluster)
{
    const int j = blockIdx.x * 256 + threadIdx.x;   // 32 blocks
    float nc = 0.8f * cluster[j] + 0.2f * counts[j];
    out_cluster[j] = nc;
    float s = nc;
#pragma unroll
    for (int m = 32; m >= 1; m >>= 1) s += __shfl_xor(s, m, 64);
    __shared__ float ls[4];
    if ((threadIdx.x & 63) == 0) ls[threadIdx.x >> 6] = s;
    __syncthreads();
    if (threadIdx.x == 0) atomicAdd(total_ws, ls[0] + ls[1] + ls[2] + ls[3]);
}

// ---------------- K3b: smoothed / new_embed_avg / new_embed / loss --------
__global__ __launch_bounds__(256) void k_final2(
    const float* __restrict__ cluster, const float* __restrict__ counts,
    const float* __restrict__ embed_avg, const float* __restrict__ embed_sum,
    const float* __restrict__ total_ws, const float* __restrict__ loss_ws,
    float* __restrict__ out_loss, float* __restrict__ out_eavg,
    float* __restrict__ out_embed)
{
    const int e = blockIdx.x * 256 + threadIdx.x;   // 2048 blocks -> 524288
    const int j = e & (NCODE - 1);
    const int kk = e >> 13;
    const float total = *total_ws;
    float nc = 0.8f * cluster[j] + 0.2f * counts[j];
    float smoothed = (nc + 1e-5f) / (total + 0.08192f) * total;
    float es = embed_sum[(size_t)j * 64 + kk];      // [code][k] -> [k][code] remap
    float ea = 0.8f * embed_avg[e] + 0.2f * es;
    out_eavg[e]  = ea;
    out_embed[e] = ea / smoothed;
    if (e == 0) *out_loss = *loss_ws * (1.0f / 2097152.0f);
}

extern "C" void kernel_launch(void* const* d_in, const int* in_sizes, int n_in,
                              void* d_out, int out_size, void* d_ws, size_t ws_size,
                              hipStream_t stream) {
    (void)in_sizes; (void)n_in; (void)out_size; (void)ws_size;
    const float* x        = (const float*)d_in[0];   // (32,16,64,64)
    const float* embed    = (const float*)d_in[1];   // (64,8192)
    const float* pos      = (const float*)d_in[2];   // (2048,256)
    const float* cluster  = (const float*)d_in[3];   // (8192,)
    const float* eavg     = (const float*)d_in[4];   // (64,8192)
    float* out = (float*)d_out;                      // fp32 outputs, concatenated

    char* ws = (char*)d_ws;
    float* w_loss   = (float*)(ws + WS_LOSS);
    float* w_total  = (float*)(ws + WS_TOTAL);
    float* w_se     = (float*)(ws + WS_SE);
    float* w_counts = (float*)(ws + WS_COUNTS);
    int*   w_ind    = (int*)  (ws + WS_IND);
    float* w_esum   = (float*)(ws + WS_ESUM);
    unsigned short* w_bh = (unsigned short*)(ws + WS_BH);
    unsigned short* w_bm = (unsigned short*)(ws + WS_BM);
    unsigned short* w_bl = (unsigned short*)(ws + WS_BL);

    // zero accumulators (ws is poisoned 0xAA before every launch)
    hipMemsetAsync(ws + WS_LOSS,   0, 8, stream);
    hipMemsetAsync(ws + WS_COUNTS, 0, 32768, stream);
    hipMemsetAsync(ws + WS_ESUM,   0, 2097152, stream);

    k_prep_embed<<<128, 256, 0, stream>>>(embed, w_se, w_ind, w_bh, w_bm, w_bl);
    k_argmin_mfma<<<NROWS / 128, 256, 0, stream>>>(
        x, pos, w_bh, w_bm, w_bl, w_se, w_ind, out + OUT_IND);
    k_quant<<<NROWS / 4, 256, 0, stream>>>(x, pos, w_bh, w_bm, w_bl, w_ind,
                                           w_esum, w_counts, w_loss, out + OUT_Q);
    k_final1<<<NCODE / 256, 256, 0, stream>>>(cluster, w_counts, w_total,
                                              out + OUT_CLUSTER);
    k_final2<<<524288 / 256, 256, 0, stream>>>(cluster, w_counts, eavg, w_esum,
                                               w_total, w_loss, out + OUT_LOSS,
                                               out + OUT_EAVG, out + OUT_EMBED);
}

// Round 8
// 326.192 us; speedup vs baseline: 2.8767x; 1.4620x over previous
//
#include <hip/hip_runtime.h>
#include <hip/hip_bf16.h>

#define NROWS   32768          // 32*16*64 rows of dim 64
#define NCODE   8192
#define NSPL    4              // code-dimension splits (occupancy: 4 blocks/CU)
#define CSPL    (NCODE / NSPL) // 2048 codes per block
#define CHUNKS  (CSPL / 32)    // 64 LDS chunks of 32 codes

// d_out element offsets (FLOAT32 elements):
// quantize(2097152), ind(32768), loss(1), cluster(8192), eavg(524288), embed(524288)
#define OUT_Q        0
#define OUT_IND      2097152
#define OUT_LOSS     2129920
#define OUT_CLUSTER  2129921
#define OUT_EAVG     2138113
#define OUT_EMBED    2662401

// workspace byte offsets — total 5,439,552 bytes (R7 level)
#define WS_LOSS     0            // f32 [1] (zeroed)
#define WS_TOTAL    4            // f32 [1] (zeroed)
#define WS_SE       64           // f32 [8192]  ||e_j||^2
#define WS_COUNTS   32832        // f32 [8192]  (zeroed)
#define WS_IND      65600        // i32 [32768]
#define WS_ESUM     196672       // f32 [8192][64] ([code][k], zeroed)
#define WS_PBEST    2293824      // f32 [4][32768] partial best dist
#define WS_PIDX     2818112      // i32 [4][32768] partial best idx
#define WS_BH       3342400      // bf16 bits [8192][64] embed^T high split
#define WS_BM       4390976      // bf16 bits [8192][64] mid split
// end: 5,439,552

typedef short v8s __attribute__((ext_vector_type(8)));
typedef float v4f __attribute__((ext_vector_type(4)));
#define MFMA16 __builtin_amdgcn_mfma_f32_16x16x32_bf16

__device__ __forceinline__ int pos_off(int c, int R, int k) {
    // pos_emb[(R>>2)*16 + (k>>2)][c*16 + (R&3)*4 + (k&3)], row stride 256
    return (((R >> 2) * 16 + (k >> 2)) << 8) + (c << 4) + ((R & 3) << 2) + (k & 3);
}

__device__ __forceinline__ unsigned short f2bfbits(float v) {
    __hip_bfloat16 h = __float2bfloat16(v);           // RNE
    union { __hip_bfloat16 h; unsigned short u; } c; c.h = h; return c.u;
}
__device__ __forceinline__ float bfbits2f(unsigned short u) {
    union { unsigned short u; __hip_bfloat16 h; } c; c.u = u; return __bfloat162float(c.h);
}

// ---------------- K0: ind=0, ||e_j||^2 (bit-identical chain), B' splits ---
__global__ __launch_bounds__(256) void k_prep_embed(
    const float* __restrict__ embed, float* __restrict__ se, int* __restrict__ ind,
    unsigned short* __restrict__ Bh, unsigned short* __restrict__ Bm)
{
    const int t = blockIdx.x * 256 + threadIdx.x;   // 128 blocks -> 0..32767
    ind[t] = 0;
    if (t < NCODE) {
        float s = 0.f;
#pragma unroll
        for (int k = 0; k < 64; ++k) {
            float v = embed[(size_t)k * NCODE + t];
            s = fmaf(v, v, s);                        // same chain as R5..R7 (passed)
            unsigned short uh = f2bfbits(v);  float r1 = v - bfbits2f(uh);
            unsigned short um = f2bfbits(r1);
            Bh[t * 64 + k] = uh; Bm[t * 64 + k] = um;
        }
        se[t] = s;
    }
}

// ---------------- K1: MFMA GEMM-argmin, reg A-frags, LDS B dbuf, NSPL=4 ---
// Grid 1024: rb = blk>>2 (128 rows), split = blk&3 (2048 codes).
// 4 waves; wave owns 32 rows (2 m-tiles). A-frags built straight from global.
__global__ __launch_bounds__(256) void k_argmin_mfma(
    const float* __restrict__ x, const float* __restrict__ pos,
    const unsigned short* __restrict__ Bh, const unsigned short* __restrict__ Bm,
    const float* __restrict__ se,
    float* __restrict__ part_best, int* __restrict__ part_idx)
{
    __shared__ __align__(16) short lB[2 * 2 * 32 * 72];   // dbuf x {h,m} x 32 codes
    const int tid = threadIdx.x;
    const int row0  = (blockIdx.x >> 2) * 128;
    const int split = blockIdx.x & 3;
    const int w = tid >> 6, lane = tid & 63;
    const int quad = lane >> 4, l15 = lane & 15;
    const int jbeg = split * CSPL;

    // ---- A-frags direct from global: af[mt][h/m][khalf]; same per-element
    // split math as R7 (h,m bitwise identical; low split dropped: see theory)
    v8s af[2][2][2];
    float sqf[2];
#pragma unroll
    for (int mt = 0; mt < 2; ++mt) {
        const int n = row0 + w * 32 + mt * 16 + l15;
        const int c = (n >> 6) & 15, R = n & 63;
        const float* xrow = x + (size_t)n * 64;
        const float* prow = pos + ((R >> 2) * 16) * 256 + c * 16 + (R & 3) * 4;
        float sq = 0.f;
#pragma unroll
        for (int kh = 0; kh < 2; ++kh) {
            const int kb = kh * 32 + quad * 8;         // frag k-base
            const float4 x0 = *(const float4*)(xrow + kb);
            const float4 x1 = *(const float4*)(xrow + kb + 4);
            const float4 p0 = *(const float4*)(prow + (kb >> 2) * 256);
            const float4 p1 = *(const float4*)(prow + (kb >> 2) * 256 + 256);
            float vv[8] = {x0.x + p0.x, x0.y + p0.y, x0.z + p0.z, x0.w + p0.w,
                           x1.x + p1.x, x1.y + p1.y, x1.z + p1.z, x1.w + p1.w};
            v8s hf, mf;
#pragma unroll
            for (int i = 0; i < 8; ++i) {
                unsigned short uh = f2bfbits(vv[i]);
                float r1 = vv[i] - bfbits2f(uh);
                unsigned short um = f2bfbits(r1);
                hf[i] = (short)uh; mf[i] = (short)um;
                sq = fmaf(vv[i], vv[i], sq);
            }
            af[mt][0][kh] = hf; af[mt][1][kh] = mf;
        }
        sq += __shfl_xor(sq, 16, 64);                  // sum the 4 quads' k-parts
        sq += __shfl_xor(sq, 32, 64);                  // (row-const shift: argmin-inv)
        sqf[mt] = sq;
    }
    float sxr[2][4];
#pragma unroll
    for (int mt = 0; mt < 2; ++mt)
#pragma unroll
        for (int r = 0; r < 4; ++r)
            sxr[mt][r] = __shfl(sqf[mt], quad * 4 + r, 64);  // C-row = quad*4+reg

    // ---- stream B: 32-code chunks, LDS double-buffer, register prefetch ----
    const int ct = tid >> 3, ks = tid & 7;             // staging: code, 16B slot
    const int dst = ct * 72 + ks * 8;
    float best[2][4]; int bidx[2][4];
#pragma unroll
    for (int mt = 0; mt < 2; ++mt)
#pragma unroll
        for (int r = 0; r < 4; ++r) { best[mt][r] = 3.402823466e38f; bidx[mt][r] = 0; }

    {   // prologue: chunk 0 -> buf 0
        const size_t g = (size_t)(jbeg + ct) * 64 + ks * 8;
        int4 q0 = *(const int4*)(Bh + g);
        int4 q1 = *(const int4*)(Bm + g);
        *(int4*)&lB[dst] = q0;
        *(int4*)&lB[2304 + dst] = q1;
    }
    float cse0 = se[jbeg + l15], cse1 = se[jbeg + 16 + l15];
    __syncthreads();

    int buf = 0;
    for (int c = 0; c < CHUNKS; ++c) {
        int4 q0, q1; float nse0 = 0.f, nse1 = 0.f;
        if (c < CHUNKS - 1) {                          // prefetch next chunk
            const int n0n = jbeg + (c + 1) * 32;
            const size_t g = (size_t)(n0n + ct) * 64 + ks * 8;
            q0 = *(const int4*)(Bh + g);
            q1 = *(const int4*)(Bm + g);
            nse0 = se[n0n + l15]; nse1 = se[n0n + 16 + l15];
        }
        const short* bb = &lB[buf * 4608];
#pragma unroll
        for (int t16 = 0; t16 < 2; ++t16) {
            const int boff = (t16 * 16 + l15) * 72 + quad * 8;
            const v8s bh0 = *(const v8s*)&bb[boff];
            const v8s bh1 = *(const v8s*)&bb[boff + 32];
            const v8s bm0 = *(const v8s*)&bb[2304 + boff];
            const v8s bm1 = *(const v8s*)&bb[2304 + boff + 32];
            const float sev = t16 ? cse1 : cse0;
            const int j = jbeg + c * 32 + t16 * 16 + l15;
#pragma unroll
            for (int mt = 0; mt < 2; ++mt) {           // 4 products: mm+mh | hm+hh
                v4f a1 = {0.f, 0.f, 0.f, 0.f}, a2 = {0.f, 0.f, 0.f, 0.f};
                a1 = MFMA16(af[mt][1][0], bm0, a1, 0, 0, 0);
                a1 = MFMA16(af[mt][1][1], bm1, a1, 0, 0, 0);
                a1 = MFMA16(af[mt][1][0], bh0, a1, 0, 0, 0);
                a1 = MFMA16(af[mt][1][1], bh1, a1, 0, 0, 0);
                a2 = MFMA16(af[mt][0][0], bm0, a2, 0, 0, 0);
                a2 = MFMA16(af[mt][0][1], bm1, a2, 0, 0, 0);
                a2 = MFMA16(af[mt][0][0], bh0, a2, 0, 0, 0);
                a2 = MFMA16(af[mt][0][1], bh1, a2, 0, 0, 0);
#pragma unroll
                for (int r = 0; r < 4; ++r) {
                    float d = fmaf(-2.f, a1[r], fmaf(-2.f, a2[r], sxr[mt][r])) + sev;
                    if (d < best[mt][r]) { best[mt][r] = d; bidx[mt][r] = j; }
                }
            }
        }
        if (c < CHUNKS - 1) {                          // store prefetch, swap
            const int nb = buf ^ 1;
            *(int4*)&lB[nb * 4608 + dst] = q0;
            *(int4*)&lB[nb * 4608 + 2304 + dst] = q1;
            cse0 = nse0; cse1 = nse1;
            __syncthreads();
            buf = nb;
        }
    }

    // reduce over the 16 lanes sharing each output row; lower idx wins ties
#pragma unroll
    for (int mt = 0; mt < 2; ++mt)
#pragma unroll
    for (int r = 0; r < 4; ++r) {
        float bv = best[mt][r]; int bi = bidx[mt][r];
#pragma unroll
        for (int m = 8; m >= 1; m >>= 1) {
            float ov = __shfl_xor(bv, m, 64);
            int   oi = __shfl_xor(bi, m, 64);
            if (ov < bv || (ov == bv && oi < bi)) { bv = ov; bi = oi; }
        }
        if (l15 == 0) {
            const int row = row0 + w * 32 + mt * 16 + quad * 4 + r;
            part_best[split * NROWS + row] = bv;
            part_idx [split * NROWS + row] = bi;
        }
    }
}

// ---------------- K1b: merge the 4 split partials -------------------------
__global__ __launch_bounds__(256) void k_reduce(
    const float* __restrict__ part_best, const int* __restrict__ part_idx,
    int* __restrict__ ind, float* __restrict__ out_ind)
{
    const int n = blockIdx.x * 256 + threadIdx.x;   // 128 blocks
    float bv = part_best[n];
    int   bi = part_idx[n];
#pragma unroll
    for (int s = 1; s < NSPL; ++s) {
        float v = part_best[s * NROWS + n];
        int   i = part_idx [s * NROWS + n];
        if (v < bv || (v == bv && i < bi)) { bv = v; bi = i; }  // lower idx wins
    }
    ind[n] = bi;
    out_ind[n] = (float)bi;
}

// ---------------- K2: quantize gather + loss + EMA scatter ----------------
__global__ __launch_bounds__(256) void k_quant(
    const float* __restrict__ x, const float* __restrict__ pos,
    const unsigned short* __restrict__ Bh, const unsigned short* __restrict__ Bm,
    const int* __restrict__ ind,
    float* __restrict__ embed_sum, float* __restrict__ counts,
    float* __restrict__ loss_ws, float* __restrict__ out_q)
{
    const int tid = threadIdx.x;
    const int rr = tid >> 6, k = tid & 63;       // 4 rows x 64 dims
    const int n = blockIdx.x * 4 + rr;
    int idx = ind[n];
    idx = idx < 0 ? 0 : (idx > NCODE - 1 ? NCODE - 1 : idx);  // defensive clamp
    const size_t eo = (size_t)idx * 64 + k;
    const float qv = bfbits2f(Bh[eo]) + bfbits2f(Bm[eo]);   // err ~1e-5 << 0.03 thr
    const float xv = x[(size_t)n * 64 + k];
    out_q[(size_t)n * 64 + k] = qv;

    const int c = (n >> 6) & 15, R = n & 63;
    const float fv = xv + pos[pos_off(c, R, k)];
    atomicAdd(&embed_sum[eo], fv);               // [code][k]: row-contiguous lines
    if (k == 0) atomicAdd(&counts[idx], 1.0f);

    float sq = (qv - xv) * (qv - xv);
#pragma unroll
    for (int m = 32; m >= 1; m >>= 1) sq += __shfl_xor(sq, m, 64);
    __shared__ float ls[4];
    if ((tid & 63) == 0) ls[tid >> 6] = sq;
    __syncthreads();
    if (tid == 0) atomicAdd(loss_ws, ls[0] + ls[1] + ls[2] + ls[3]);
}

// ---------------- K3a: new_cluster + total --------------------------------
__global__ __launch_bounds__(256) void k_final1(
    const float* __restrict__ cluster, const float* __restrict__ counts,
    float* __restrict__ total_ws, float* __restrict__ out_cluster)
{
    const int j = blockIdx.x * 256 + threadIdx.x;   // 32 blocks
    float nc = 0.8f * cluster[j] + 0.2f * counts[j];
    out_cluster[j] = nc;
    float s = nc;
#pragma unroll
    for (int m = 32; m >= 1; m >>= 1) s += __shfl_xor(s, m, 64);
    __shared__ float ls[4];
    if ((threadIdx.x & 63) == 0) ls[threadIdx.x >> 6] = s;
    __syncthreads();
    if (threadIdx.x == 0) atomicAdd(total_ws, ls[0] + ls[1] + ls[2] + ls[3]);
}

// ---------------- K3b: smoothed / new_embed_avg / new_embed / loss --------
__global__ __launch_bounds__(256) void k_final2(
    const float* __restrict__ cluster, const float* __restrict__ counts,
    const float* __restrict__ embed_avg, const float* __restrict__ embed_sum,
    const float* __restrict__ total_ws, const float* __restrict__ loss_ws,
    float* __restrict__ out_loss, float* __restrict__ out_eavg,
    float* __restrict__ out_embed)
{
    const int e = blockIdx.x * 256 + threadIdx.x;   // 2048 blocks -> 524288
    const int j = e & (NCODE - 1);
    const int kk = e >> 13;
    const float total = *total_ws;
    float nc = 0.8f * cluster[j] + 0.2f * counts[j];
    float smoothed = (nc + 1e-5f) / (total + 0.08192f) * total;
    float es = embed_sum[(size_t)j * 64 + kk];      // [code][k] -> [k][code] remap
    float ea = 0.8f * embed_avg[e] + 0.2f * es;
    out_eavg[e]  = ea;
    out_embed[e] = ea / smoothed;
    if (e == 0) *out_loss = *loss_ws * (1.0f / 2097152.0f);
}

extern "C" void kernel_launch(void* const* d_in, const int* in_sizes, int n_in,
                              void* d_out, int out_size, void* d_ws, size_t ws_size,
                              hipStream_t stream) {
    (void)in_sizes; (void)n_in; (void)out_size; (void)ws_size;
    const float* x        = (const float*)d_in[0];   // (32,16,64,64)
    const float* embed    = (const float*)d_in[1];   // (64,8192)
    const float* pos      = (const float*)d_in[2];   // (2048,256)
    const float* cluster  = (const float*)d_in[3];   // (8192,)
    const float* eavg     = (const float*)d_in[4];   // (64,8192)
    float* out = (float*)d_out;                      // fp32 outputs, concatenated

    char* ws = (char*)d_ws;
    float* w_loss   = (float*)(ws + WS_LOSS);
    float* w_total  = (float*)(ws + WS_TOTAL);
    float* w_se     = (float*)(ws + WS_SE);
    float* w_counts = (float*)(ws + WS_COUNTS);
    int*   w_ind    = (int*)  (ws + WS_IND);
    float* w_esum   = (float*)(ws + WS_ESUM);
    float* w_pbest  = (float*)(ws + WS_PBEST);
    int*   w_pidx   = (int*)  (ws + WS_PIDX);
    unsigned short* w_bh = (unsigned short*)(ws + WS_BH);
    unsigned short* w_bm = (unsigned short*)(ws + WS_BM);

    // zero accumulators (ws is poisoned 0xAA before every launch)
    hipMemsetAsync(ws + WS_LOSS,   0, 8, stream);
    hipMemsetAsync(ws + WS_COUNTS, 0, 32768, stream);
    hipMemsetAsync(ws + WS_ESUM,   0, 2097152, stream);

    k_prep_embed<<<128, 256, 0, stream>>>(embed, w_se, w_ind, w_bh, w_bm);
    k_argmin_mfma<<<(NROWS / 128) * NSPL, 256, 0, stream>>>(
        x, pos, w_bh, w_bm, w_se, w_pbest, w_pidx);
    k_reduce<<<NROWS / 256, 256, 0, stream>>>(w_pbest, w_pidx, w_ind,
                                              out + OUT_IND);
    k_quant<<<NROWS / 4, 256, 0, stream>>>(x, pos, w_bh, w_bm, w_ind,
                                           w_esum, w_counts, w_loss, out + OUT_Q);
    k_final1<<<NCODE / 256, 256, 0, stream>>>(cluster, w_counts, w_total,
                                              out + OUT_CLUSTER);
    k_final2<<<524288 / 256, 256, 0, stream>>>(cluster, w_counts, eavg, w_esum,
                                               w_total, w_loss, out + OUT_LOSS,
                                               out + OUT_EAVG, out + OUT_EMBED);
}